// Round 24
// baseline (13278.705 us; speedup 1.0000x reference)
//
#include <hip/hip_runtime.h>
#include <hip/hip_fp16.h>
#include <math.h>

#define Bz 16
#define Tz 1024
#define Ez 768
#define E3 2304
#define Vz 50257
#define NBK 256          // 256 blocks: layer (2) x batch-group (2) x col-group (64)
#define LN_EPS 1e-5f
#define VEC (Bz*Ez)      // 12288 floats per full h vector
#define VECW 6144        // packed fp16: u32 words per full h vector
#define EP 772           // padded LDS row stride (fp32)
#define BS 8             // batches per block
#define CW 12            // columns per block

__device__ __forceinline__ float dot4acc(float acc, float4 w, float4 h){
  acc = fmaf(w.x,h.x,acc); acc = fmaf(w.y,h.y,acc);
  acc = fmaf(w.z,h.z,acc); acc = fmaf(w.w,h.w,acc);
  return acc;
}
__device__ __forceinline__ float sigm(float x){ return 1.0f/(1.0f+expf(-x)); }

__device__ __forceinline__ unsigned pack2(float a, float b){
  __half2 h = __floats2half2_rn(a, b);
  union{__half2 h2; unsigned u;} cv; cv.h2 = h; return cv.u;
}
__device__ __forceinline__ float2 unpack2(unsigned u){
  union{unsigned u; __half2 h2;} cv; cv.u = u;
  return __half22float2(cv.h2);
}

// ---- Staging envelope (empirical): scalar 32-bit relaxed-atomic loads with
// immediate LDS stores, <=4 outstanding per body. Byte-identical to R23. ----

__device__ __forceinline__ void stage8(const unsigned* __restrict__ src,
                                       float (*dst)[EP], int tid){
#pragma unroll
  for (int k=0;k<2;k++){
    const int u0 = tid + k*1536;
    const int u1 = u0 + 512;
    const int u2 = u0 + 1024;
    const unsigned a0 = __hip_atomic_load(src+u0, __ATOMIC_RELAXED, __HIP_MEMORY_SCOPE_AGENT);
    const unsigned a1 = __hip_atomic_load(src+u1, __ATOMIC_RELAXED, __HIP_MEMORY_SCOPE_AGENT);
    const unsigned a2 = __hip_atomic_load(src+u2, __ATOMIC_RELAXED, __HIP_MEMORY_SCOPE_AGENT);
    {const int b=u0/384, c=(u0-b*384)<<1; const float2 f=unpack2(a0); dst[b][c]=f.x; dst[b][c+1]=f.y;}
    {const int b=u1/384, c=(u1-b*384)<<1; const float2 f=unpack2(a1); dst[b][c]=f.x; dst[b][c+1]=f.y;}
    {const int b=u2/384, c=(u2-b*384)<<1; const float2 f=unpack2(a2); dst[b][c]=f.x; dst[b][c+1]=f.y;}
  }
}

__device__ __forceinline__ void stage8x2(const unsigned* __restrict__ srcX,
                                         float (*dstX)[EP],
                                         const unsigned* __restrict__ srcH,
                                         float (*dstH)[EP], int tid){
#pragma unroll
  for (int k=0;k<3;k++){
    const int u0 = tid + (k<<10);
    const int u1 = u0 + 512;
    const unsigned x0 = __hip_atomic_load(srcX+u0, __ATOMIC_RELAXED, __HIP_MEMORY_SCOPE_AGENT);
    const unsigned x1 = __hip_atomic_load(srcX+u1, __ATOMIC_RELAXED, __HIP_MEMORY_SCOPE_AGENT);
    const unsigned h0 = __hip_atomic_load(srcH+u0, __ATOMIC_RELAXED, __HIP_MEMORY_SCOPE_AGENT);
    const unsigned h1 = __hip_atomic_load(srcH+u1, __ATOMIC_RELAXED, __HIP_MEMORY_SCOPE_AGENT);
    const int b0=u0/384, c0_=(u0-b0*384)<<1;
    const int b1=u1/384, c1_=(u1-b1*384)<<1;
    {const float2 f=unpack2(x0); dstX[b0][c0_]=f.x; dstX[b0][c0_+1]=f.y;}
    {const float2 f=unpack2(x1); dstX[b1][c1_]=f.x; dstX[b1][c1_+1]=f.y;}
    {const float2 f=unpack2(h0); dstH[b0][c0_]=f.x; dstH[b0][c0_+1]=f.y;}
    {const float2 f=unpack2(h1); dstH[b1][c1_]=f.x; dstH[b1][c1_+1]=f.y;}
  }
}

__device__ __forceinline__ void zero8(float (*dst)[EP], int tid){
#pragma unroll
  for (int k=0;k<6;k++){
    const int u = tid + (k<<9);
    const int b = u/384, c = (u-b*384)<<1;
    dst[b][c] = 0.f; dst[b][c+1] = 0.f;
  }
}

// 9 rows per wave (wave-group row base wv4*9), 8 batches (bb -> 2 each).
__device__ __forceinline__ void mm9(const float (*V)[EP],
                                    const float* const (&wRow)[9],
                                    float (*gOut)[9],
                                    int wv4, int kq, int bb){
  float acc[9][2];
#pragma unroll
  for (int r=0;r<9;r++){ acc[r][0]=0.f; acc[r][1]=0.f; }
#pragma unroll 4
  for (int j=0;j<12;j++){
    const int kk = (j<<6) + (kq<<2);
    float4 w4[9];
#pragma unroll
    for (int r=0;r<9;r++) w4[r] = *(const float4*)(wRow[r] + kk);
#pragma unroll
    for (int bi=0;bi<2;bi++){
      const float4 hv = *(const float4*)&V[bb*2+bi][kk];
#pragma unroll
      for (int r=0;r<9;r++) acc[r][bi] = dot4acc(acc[r][bi], w4[r], hv);
    }
  }
#pragma unroll
  for (int r=0;r<9;r++)
#pragma unroll
    for (int bi=0;bi<2;bi++){
      float a = acc[r][bi];
      a += __shfl_xor(a,1); a += __shfl_xor(a,2);
      a += __shfl_xor(a,4); a += __shfl_xor(a,8);
      acc[r][bi]=a;
    }
  if (kq==0){
#pragma unroll
    for (int r=0;r<9;r++)
#pragma unroll
      for (int bi=0;bi<2;bi++) gOut[wv4*9+r][bb*2+bi] = acc[r][bi];
  }
}

// ---------------------------------------------------------------------------
// Persistent cooperative scan = R23 (fused phase) + SPLIT WAIT:
//  1) early poll: wave 0 polls only the PRODUCER-GROUP flags (L0 blocks:
//     own (L0,bg) group; L1 blocks: (L0,bg)+(L1,bg)) -> staging is safe.
//  2) stage (overlaps the global relay's flag aggregation + go broadcast).
//  3) check go >= s (usually already set) before compute/publish -- the
//     full barrier still guards all write-after-read buffer hazards.
//  Block 0 performs relay duty (poll all 256 -> go) BEFORE its staging.
// ---------------------------------------------------------------------------
__global__ __launch_bounds__(512) void gru_scan(
    const int* __restrict__ idx, const float* __restrict__ wte,
    const float* __restrict__ Wih, const float* __restrict__ bih,
    const float* __restrict__ Whh, const float* __restrict__ bhh,
    unsigned* __restrict__ h0g, unsigned* __restrict__ h1g,
    float* __restrict__ h1f,
    unsigned* __restrict__ flags, unsigned* __restrict__ go)
{
  __shared__ float bufX[BS][EP];      // gi input: x(s+1) (L0) / h0(s-1) (L1)
  __shared__ float bufH[BS][EP];      // gh input: own-layer h_prev
  __shared__ float gatesG[36][9];     // gh (this step)
  __shared__ float gatesI[2][36][9];  // gi ping-pong (s&1 = write slot)
  __shared__ float biasS[72];
  __shared__ float hprev[BS][CW];     // own (batch,col) h, exact fp32

  const int tid = threadIdx.x, bx = blockIdx.x;
  const int L = bx>>7, sub = bx&127;
  const int bg = sub>>6, cg = sub&63;
  const int c0 = cg*CW, b0 = bg*BS;
  const int wv = tid>>6, lane = tid&63, kq = lane&15, bb = lane>>4;
  const int wv4 = wv & 3;

  const float* WihL = Wih + (size_t)L*E3*Ez;
  const float* WhhL = Whh + (size_t)L*E3*Ez;

  // waves 0-3 -> Whh rows (gatesG); waves 4-7 -> Wih rows (gatesI).
  const float* wRow[9];
  {
    const float* Wb = (wv < 4) ? WhhL : WihL;
#pragma unroll
    for (int r=0;r<9;r++){
      const int m = wv4*9 + r, g = m/12, cc = m - g*12;
      wRow[r] = Wb + (size_t)(g*Ez + c0 + cc)*Ez;
    }
  }
  if (tid<72){
    const int mat = tid/36, mm = tid%36, g = mm/12, cc = mm-g*12;
    biasS[tid] = (mat ? bhh : bih)[L*E3 + g*Ez + c0 + cc];
  }
  if (tid<96) hprev[tid&7][tid>>3] = 0.f;

  // producer-group flag bases (for the early poll)
  const unsigned* pf0 = flags + bg*64;          // (L0,bg) group
  const unsigned* pf1 = flags + 128 + bg*64;    // (L1,bg) group

  // ---- prologue (L0): gatesI[1] <- Wih . x(0); then load x(1) ----
  if (L==0){
#pragma unroll
    for (int k=0;k<3;k++){
      const int i4 = tid + (k<<9);
      const int b = i4/192, c4 = i4 - b*192;
      const int row = idx[(b0+b)*Tz];
      *(float4*)&bufX[b][c4<<2] = *(const float4*)(wte + (size_t)row*Ez + (c4<<2));
    }
    __syncthreads();
    if (wv>=4) mm9(bufX, wRow, gatesI[1], wv4, kq, bb);
    __syncthreads();
#pragma unroll
    for (int k=0;k<3;k++){
      const int i4 = tid + (k<<9);
      const int b = i4/192, c4 = i4 - b*192;
      const int row = idx[(b0+b)*Tz + 1];
      *(float4*)&bufX[b][c4<<2] = *(const float4*)(wte + (size_t)row*Ez + (c4<<2));
    }
  }
  __syncthreads();

  for (int s=0; s<=Tz+1; ++s){
    // ---- split wait, part 1: producer-group poll (or relay for block 0) ----
    if (s>0){
      const unsigned tgt = (unsigned)s;
      if (bx==0){
        // relay duty first: aggregate all 256 flags, broadcast go
        if (tid<64){
          const unsigned* f = flags + (tid<<2);
          for(;;){
            const unsigned a0 = __hip_atomic_load(f+0, __ATOMIC_RELAXED, __HIP_MEMORY_SCOPE_AGENT);
            const unsigned a1 = __hip_atomic_load(f+1, __ATOMIC_RELAXED, __HIP_MEMORY_SCOPE_AGENT);
            const unsigned a2 = __hip_atomic_load(f+2, __ATOMIC_RELAXED, __HIP_MEMORY_SCOPE_AGENT);
            const unsigned a3 = __hip_atomic_load(f+3, __ATOMIC_RELAXED, __HIP_MEMORY_SCOPE_AGENT);
            const int ok = (a0>=tgt) & (a1>=tgt) & (a2>=tgt) & (a3>=tgt);
            if (__all(ok)) break;
            __builtin_amdgcn_s_sleep(1);
          }
          __hip_atomic_store(go + (tid<<5), tgt,
                             __ATOMIC_RELAXED, __HIP_MEMORY_SCOPE_AGENT);
        }
      } else {
        if (tid<64){
          if (L==0){
            for(;;){
              const unsigned a0 = __hip_atomic_load(pf0+tid, __ATOMIC_RELAXED, __HIP_MEMORY_SCOPE_AGENT);
              if (__all(a0>=tgt)) break;
              __builtin_amdgcn_s_sleep(2);
            }
          } else {
            for(;;){
              const unsigned a0 = __hip_atomic_load(pf0+tid, __ATOMIC_RELAXED, __HIP_MEMORY_SCOPE_AGENT);
              const unsigned a1 = __hip_atomic_load(pf1+tid, __ATOMIC_RELAXED, __HIP_MEMORY_SCOPE_AGENT);
              if (__all((a0>=tgt)&(a1>=tgt))) break;
              __builtin_amdgcn_s_sleep(2);
            }
          }
        }
      }
      __syncthreads();
    }

    // ---- activity windows ----
    const bool gG = (L==0) ? (s<=Tz-1) : (s>=2);               // gh + nonlin
    const bool gI = (L==0) ? (s<=Tz-2) : (s>=1 && s<=Tz);      // gi for next step

    // ---- stage (overlapped with the relay's go broadcast) ----
    if (L==0){
      if (s==0)            zero8(bufH, tid);
      else if (s<=Tz-1)    stage8(h0g + (size_t)((s-1)%3)*VECW + bg*3072, bufH, tid);
      // bufX holds x(s+1), prefetched (cached)
    } else {
      const unsigned* x_src = h0g + (size_t)((s-1)%3)*VECW + bg*3072;   // h0(s-1)
      const unsigned* h_src = h1g + (size_t)((s-1)&1)*VECW + bg*3072;   // h1(s-3)
      if (s>=3 && s<=Tz)      stage8x2(x_src, bufX, h_src, bufH, tid);
      else if (s==2)        { stage8(x_src, bufX, tid); zero8(bufH, tid); }
      else if (s==1)          stage8(x_src, bufX, tid);
      else if (s==Tz+1)       stage8(h_src, bufH, tid);
    }
    __syncthreads();

    // ---- split wait, part 2: confirm global go (usually already set) ----
    if (s>0 && bx!=0){
      if (tid==0){
        const unsigned* gp = go + ((bx&63)<<5);
        while (__hip_atomic_load(gp, __ATOMIC_RELAXED, __HIP_MEMORY_SCOPE_AGENT) < (unsigned)s)
          __builtin_amdgcn_s_sleep(1);
      }
      __syncthreads();
    }

    // ---- fused matmul: waves 0-3 gh, waves 4-7 gi (concurrent) ----
    if (wv<4){ if (gG) mm9(bufH, wRow, gatesG,        wv4, kq, bb); }
    else     { if (gI) mm9(bufX, wRow, gatesI[s&1],   wv4, kq, bb); }
    __syncthreads();

    // ---- nonlinearity + publish (48 threads: 8 b x 6 col-pairs) ----
    if (gG && tid<48){
      const int b = tid&7, j = tid>>3;
      float hv2[2];
#pragma unroll
      for (int e=0;e<2;e++){
        const int cc = 2*j+e;
        const float gir = gatesI[(s-1)&1][cc    ][b] + biasS[cc];
        const float giz = gatesI[(s-1)&1][12+cc][b] + biasS[12+cc];
        const float gin = gatesI[(s-1)&1][24+cc][b] + biasS[24+cc];
        const float ghr = gatesG[cc    ][b] + biasS[36+cc];
        const float ghz = gatesG[12+cc][b] + biasS[48+cc];
        const float ghn = gatesG[24+cc][b] + biasS[60+cc];
        const float r = sigm(gir+ghr);
        const float z = sigm(giz+ghz);
        const float n = tanhf(fmaf(r, ghn, gin));
        const float hp = hprev[b][cc];
        hv2[e] = fmaf(z, hp - n, n);
        hprev[b][cc] = hv2[e];
      }
      const unsigned pk = pack2(hv2[0], hv2[1]);
      if (L==0){
        unsigned* hOutW = h0g + (size_t)(s%3)*VECW;
        __hip_atomic_store(hOutW + (b0+b)*384 + cg*6 + j, pk,
                           __ATOMIC_RELAXED, __HIP_MEMORY_SCOPE_AGENT);
      } else {
        unsigned* hOutW = h1g + (size_t)((s-2)&1)*VECW;
        __hip_atomic_store(hOutW + (b0+b)*384 + cg*6 + j, pk,
                           __ATOMIC_RELAXED, __HIP_MEMORY_SCOPE_AGENT);
        if (s==Tz+1){                          // h1(Tz-1) -> fp32 for LN
          h1f[(b0+b)*Ez + c0 + 2*j    ] = hv2[0];
          h1f[(b0+b)*Ez + c0 + 2*j + 1] = hv2[1];
        }
      }
    }

    // ---- arrive: drain publish stores, then flag ----
    __syncthreads();
    if (tid==0)
      __hip_atomic_store(flags + bx, (unsigned)(s+1),
                         __ATOMIC_RELAXED, __HIP_MEMORY_SCOPE_AGENT);

    // ---- post-flag: L0 cached x(s+2) prefetch ----
    if (L==0 && s<=Tz-3){
#pragma unroll
      for (int k=0;k<3;k++){
        const int i4 = tid + (k<<9);
        const int b = i4/192, c4 = i4 - b*192;
        const int row = idx[(b0+b)*Tz + (s+2)];
        *(float4*)&bufX[b][c4<<2] = *(const float4*)(wte + (size_t)row*Ez + (c4<<2));
      }
    }
  }
}

// LayerNorm of final h1 (fp32) -> ln
__global__ __launch_bounds__(256) void finalize_ln(
    const float* __restrict__ h1, const float* __restrict__ g,
    float* __restrict__ ln)
{
  const int tid=threadIdx.x, wv=tid>>6, lane=tid&63;
  for (int b=wv; b<Bz; b+=4){
    float sum=0.f;
    for (int c=lane;c<Ez;c+=64) sum += h1[b*Ez+c];
#pragma unroll
    for (int off=32; off; off>>=1) sum += __shfl_xor(sum, off);
    const float mu = sum/(float)Ez;
    float s2=0.f;
    for (int c=lane;c<Ez;c+=64){ const float d=h1[b*Ez+c]-mu; s2=fmaf(d,d,s2); }
#pragma unroll
    for (int off=32; off; off>>=1) s2 += __shfl_xor(s2, off);
    const float inv = rsqrtf(s2/(float)Ez + LN_EPS);
    for (int c=lane;c<Ez;c+=64) ln[b*Ez+c] = (h1[b*Ez+c]-mu)*inv*g[c];
  }
}

// logits[b,v] = dot(ln[b,:], wte[v,:]) ; 64 rows per block, 16 rows per wave.
__global__ __launch_bounds__(256) void lm_head(
    const float* __restrict__ ln, const float* __restrict__ wte,
    float* __restrict__ out)
{
  __shared__ float sLn[Bz][EP];
  const int tid=threadIdx.x;
  for (int i4=tid; i4<Bz*Ez/4; i4+=256){
    const int b = i4/(Ez/4), c = (i4 - b*(Ez/4))<<2;
    *(float4*)(&sLn[b][c]) = *(const float4*)(ln + b*Ez + c);
  }
  __syncthreads();
  const int wv=tid>>6, lane=tid&63, rr=lane>>4, cl=lane&15;
  const int vbase = blockIdx.x*64 + wv*16 + rr;
  float acc[4][16];
#pragma unroll
  for (int k=0;k<4;k++)
#pragma unroll
    for (int b=0;b<16;b++) acc[k][b]=0.f;

  for (int j=0;j<12;j++){
    const int c = (cl<<2) + (j<<6);
    float4 w4[4];
#pragma unroll
    for (int k=0;k<4;k++){
      const int v = vbase + 4*k;
      if (v < Vz) w4[k] = *(const float4*)(wte + (size_t)v*Ez + c);
      else { w4[k].x=w4[k].y=w4[k].z=w4[k].w=0.f; }
    }
#pragma unroll
    for (int b=0;b<16;b++){
      const float4 hv = *(const float4*)(&sLn[b][c]);
#pragma unroll
      for (int k=0;k<4;k++) acc[k][b] = dot4acc(acc[k][b], w4[k], hv);
    }
  }
#pragma unroll
  for (int off=1; off<16; off<<=1)
#pragma unroll
    for (int k=0;k<4;k++)
#pragma unroll
      for (int b=0;b<16;b++) acc[k][b] += __shfl_xor(acc[k][b], off);

  if (cl==0){
#pragma unroll
    for (int k=0;k<4;k++){
      const int v = vbase + 4*k;
      if (v < Vz){
#pragma unroll
        for (int b=0;b<16;b++) out[(size_t)b*Vz + v] = acc[k][b];
      }
    }
  }
}

extern "C" void kernel_launch(void* const* d_in, const int* in_sizes, int n_in,
                              void* d_out, int out_size, void* d_ws, size_t ws_size,
                              hipStream_t stream) {
  const int*   idx = (const int*)  d_in[0];
  const float* wte = (const float*)d_in[1];
  const float* Wih = (const float*)d_in[2];
  const float* bih = (const float*)d_in[3];
  const float* Whh = (const float*)d_in[4];
  const float* bhh = (const float*)d_in[5];
  const float* g   = (const float*)d_in[6];
  float* out = (float*)d_out;

  unsigned* flags = (unsigned*)d_ws;            // words [0,256)
  unsigned* go    = (unsigned*)d_ws + 512;      // words [512,2560): 64 lines
  unsigned* h0g   = (unsigned*)d_ws + 4096;     // 3 x 6144 words (triple buf)
  unsigned* h1g   = h0g + 3*VECW;               // 2 x 6144 words
  float*    h1f   = (float*)(h1g + 2*VECW);     // B*E fp32 final h1
  float*    ln    = h1f + VEC;                  // B*E fp32

  (void)hipMemsetAsync(d_ws, 0, 16384, stream); // reset flags + go lines

  void* args[] = {(void*)&idx,(void*)&wte,(void*)&Wih,(void*)&bih,
                  (void*)&Whh,(void*)&bhh,(void*)&h0g,(void*)&h1g,
                  (void*)&h1f,(void*)&flags,(void*)&go};
  (void)hipLaunchCooperativeKernel((void*)gru_scan, dim3(NBK), dim3(512), args, 0, stream);

  finalize_ln<<<1, 256, 0, stream>>>(h1f, g, ln);
  lm_head<<<786, 256, 0, stream>>>(ln, wte, out);
}

// Round 25
// 10702.573 us; speedup vs baseline: 1.2407x; 1.2407x over previous
//
#include <hip/hip_runtime.h>
#include <hip/hip_fp16.h>
#include <math.h>

#define Bz 16
#define Tz 1024
#define Ez 768
#define E3 2304
#define Vz 50257
#define NBK 256          // 256 blocks: layer (2) x batch-group (2) x col-group (64)
#define LN_EPS 1e-5f
#define VEC (Bz*Ez)      // 12288 floats per full h vector
#define VECW 6144        // packed fp16: u32 words per full h vector
#define EP 772           // padded LDS row stride (fp32)
#define BS 8             // batches per block
#define CW 12            // columns per block

__device__ __forceinline__ float dot4acc(float acc, float4 w, float4 h){
  acc = fmaf(w.x,h.x,acc); acc = fmaf(w.y,h.y,acc);
  acc = fmaf(w.z,h.z,acc); acc = fmaf(w.w,h.w,acc);
  return acc;
}
__device__ __forceinline__ float sigm(float x){ return 1.0f/(1.0f+expf(-x)); }

__device__ __forceinline__ unsigned pack2(float a, float b){
  __half2 h = __floats2half2_rn(a, b);
  union{__half2 h2; unsigned u;} cv; cv.h2 = h; return cv.u;
}
__device__ __forceinline__ float2 unpack2(unsigned u){
  union{unsigned u; __half2 h2;} cv; cv.u = u;
  return __half22float2(cv.h2);
}

// ---- Staging envelope (empirical): scalar 32-bit relaxed-atomic loads with
// immediate LDS stores, <=4 outstanding per body. Byte-identical to R23. ----

__device__ __forceinline__ void stage8(const unsigned* __restrict__ src,
                                       float (*dst)[EP], int tid){
#pragma unroll
  for (int k=0;k<2;k++){
    const int u0 = tid + k*1536;
    const int u1 = u0 + 512;
    const int u2 = u0 + 1024;
    const unsigned a0 = __hip_atomic_load(src+u0, __ATOMIC_RELAXED, __HIP_MEMORY_SCOPE_AGENT);
    const unsigned a1 = __hip_atomic_load(src+u1, __ATOMIC_RELAXED, __HIP_MEMORY_SCOPE_AGENT);
    const unsigned a2 = __hip_atomic_load(src+u2, __ATOMIC_RELAXED, __HIP_MEMORY_SCOPE_AGENT);
    {const int b=u0/384, c=(u0-b*384)<<1; const float2 f=unpack2(a0); dst[b][c]=f.x; dst[b][c+1]=f.y;}
    {const int b=u1/384, c=(u1-b*384)<<1; const float2 f=unpack2(a1); dst[b][c]=f.x; dst[b][c+1]=f.y;}
    {const int b=u2/384, c=(u2-b*384)<<1; const float2 f=unpack2(a2); dst[b][c]=f.x; dst[b][c+1]=f.y;}
  }
}

__device__ __forceinline__ void zero8(float (*dst)[EP], int tid){
#pragma unroll
  for (int k=0;k<6;k++){
    const int u = tid + (k<<9);
    const int b = u/384, c = (u-b*384)<<1;
    dst[b][c] = 0.f; dst[b][c+1] = 0.f;
  }
}

// 9 rows per wave (wave-group row base wv4*9), 8 batches (bb -> 2 each).
__device__ __forceinline__ void mm9(const float (*V)[EP],
                                    const float* const (&wRow)[9],
                                    float (*gOut)[9],
                                    int wv4, int kq, int bb){
  float acc[9][2];
#pragma unroll
  for (int r=0;r<9;r++){ acc[r][0]=0.f; acc[r][1]=0.f; }
#pragma unroll 4
  for (int j=0;j<12;j++){
    const int kk = (j<<6) + (kq<<2);
    float4 w4[9];
#pragma unroll
    for (int r=0;r<9;r++) w4[r] = *(const float4*)(wRow[r] + kk);
#pragma unroll
    for (int bi=0;bi<2;bi++){
      const float4 hv = *(const float4*)&V[bb*2+bi][kk];
#pragma unroll
      for (int r=0;r<9;r++) acc[r][bi] = dot4acc(acc[r][bi], w4[r], hv);
    }
  }
#pragma unroll
  for (int r=0;r<9;r++)
#pragma unroll
    for (int bi=0;bi<2;bi++){
      float a = acc[r][bi];
      a += __shfl_xor(a,1); a += __shfl_xor(a,2);
      a += __shfl_xor(a,4); a += __shfl_xor(a,8);
      acc[r][bi]=a;
    }
  if (kq==0){
#pragma unroll
    for (int r=0;r<9;r++)
#pragma unroll
      for (int bi=0;bi<2;bi++) gOut[wv4*9+r][bb*2+bi] = acc[r][bi];
  }
}

// ---------------------------------------------------------------------------
// Persistent cooperative scan = R23 (fused phase, two-level relay barrier)
// with L1 LAG 3 and L1's h0-stage moved POST-FLAG:
//  L0 at step s: critical{stage h0(s-1) -> gG||gI(x(s+1)) -> h0(s)};
//                post-flag: cached x(s+2) prefetch.
//  L1 at step s: critical{stage h1(s-4) only -> gG||gI(bufX=h0(s-2)) ->
//                h1(s-3)}; post-flag: stage h0(s-1) -> bufX (visibility by
//                the ALREADY-detected go(s); no extra polling).
//  h0 quadruple-buffered (%4: post-flag reader of slot (s-1)%4 finishes
//  before first rewriter h0(s+3), guarded by our flag(s+3)); h1 double.
// ---------------------------------------------------------------------------
__global__ __launch_bounds__(512) void gru_scan(
    const int* __restrict__ idx, const float* __restrict__ wte,
    const float* __restrict__ Wih, const float* __restrict__ bih,
    const float* __restrict__ Whh, const float* __restrict__ bhh,
    unsigned* __restrict__ h0g, unsigned* __restrict__ h1g,
    float* __restrict__ h1f,
    unsigned* __restrict__ flags, unsigned* __restrict__ go)
{
  __shared__ float bufX[BS][EP];      // gi input: x(s+1) (L0) / h0(s-2) (L1)
  __shared__ float bufH[BS][EP];      // gh input: own-layer h_prev
  __shared__ float gatesG[36][9];     // gh (this step)
  __shared__ float gatesI[2][36][9];  // gi ping-pong (s&1 = write slot)
  __shared__ float biasS[72];
  __shared__ float hprev[BS][CW];     // own (batch,col) h, exact fp32

  const int tid = threadIdx.x, bx = blockIdx.x;
  const int L = bx>>7, sub = bx&127;
  const int bg = sub>>6, cg = sub&63;
  const int c0 = cg*CW, b0 = bg*BS;
  const int wv = tid>>6, lane = tid&63, kq = lane&15, bb = lane>>4;
  const int wv4 = wv & 3;

  const float* WihL = Wih + (size_t)L*E3*Ez;
  const float* WhhL = Whh + (size_t)L*E3*Ez;

  // waves 0-3 -> Whh rows (gatesG); waves 4-7 -> Wih rows (gatesI).
  const float* wRow[9];
  {
    const float* Wb = (wv < 4) ? WhhL : WihL;
#pragma unroll
    for (int r=0;r<9;r++){
      const int m = wv4*9 + r, g = m/12, cc = m - g*12;
      wRow[r] = Wb + (size_t)(g*Ez + c0 + cc)*Ez;
    }
  }
  if (tid<72){
    const int mat = tid/36, mm = tid%36, g = mm/12, cc = mm-g*12;
    biasS[tid] = (mat ? bhh : bih)[L*E3 + g*Ez + c0 + cc];
  }
  if (tid<96) hprev[tid&7][tid>>3] = 0.f;

  // ---- prologue (L0): gatesI[1] <- Wih . x(0); then load x(1) ----
  if (L==0){
#pragma unroll
    for (int k=0;k<3;k++){
      const int i4 = tid + (k<<9);
      const int b = i4/192, c4 = i4 - b*192;
      const int row = idx[(b0+b)*Tz];
      *(float4*)&bufX[b][c4<<2] = *(const float4*)(wte + (size_t)row*Ez + (c4<<2));
    }
    __syncthreads();
    if (wv>=4) mm9(bufX, wRow, gatesI[1], wv4, kq, bb);
    __syncthreads();
#pragma unroll
    for (int k=0;k<3;k++){
      const int i4 = tid + (k<<9);
      const int b = i4/192, c4 = i4 - b*192;
      const int row = idx[(b0+b)*Tz + 1];
      *(float4*)&bufX[b][c4<<2] = *(const float4*)(wte + (size_t)row*Ez + (c4<<2));
    }
  }
  __syncthreads();

  for (int s=0; s<=Tz+2; ++s){
    // ---- grid wait (two-level relay + replicated go lines, verbatim) ----
    if (s>0){
      const unsigned tgt = (unsigned)s;
      if (bx==0){
        if (tid<64){
          const unsigned* f = flags + (tid<<2);
          for(;;){
            const unsigned a0 = __hip_atomic_load(f+0, __ATOMIC_RELAXED, __HIP_MEMORY_SCOPE_AGENT);
            const unsigned a1 = __hip_atomic_load(f+1, __ATOMIC_RELAXED, __HIP_MEMORY_SCOPE_AGENT);
            const unsigned a2 = __hip_atomic_load(f+2, __ATOMIC_RELAXED, __HIP_MEMORY_SCOPE_AGENT);
            const unsigned a3 = __hip_atomic_load(f+3, __ATOMIC_RELAXED, __HIP_MEMORY_SCOPE_AGENT);
            const int ok = (a0>=tgt) & (a1>=tgt) & (a2>=tgt) & (a3>=tgt);
            if (__all(ok)) break;
            __builtin_amdgcn_s_sleep(1);
          }
          __hip_atomic_store(go + (tid<<5), tgt,
                             __ATOMIC_RELAXED, __HIP_MEMORY_SCOPE_AGENT);
        }
      } else {
        if (tid==0){
          const unsigned* gp = go + ((bx&63)<<5);
          while (__hip_atomic_load(gp, __ATOMIC_RELAXED, __HIP_MEMORY_SCOPE_AGENT) < tgt)
            __builtin_amdgcn_s_sleep(2);
        }
      }
      __syncthreads();
    }

    // ---- activity windows ----
    const bool gG = (L==0) ? (s<=Tz-1) : (s>=3);               // gh + nonlin
    const bool gI = (L==0) ? (s<=Tz-2) : (s>=2 && s<=Tz+1);    // gi for next step

    // ---- critical stage: OWN-layer h only ----
    if (L==0){
      if (s==0)            zero8(bufH, tid);
      else if (s<=Tz-1)    stage8(h0g + (size_t)((s-1)&3)*VECW + bg*3072, bufH, tid);
      // bufX holds x(s+1), prefetched (cached)
    } else {
      if (s==3)                 zero8(bufH, tid);
      else if (s>=4 && s<=Tz+2) stage8(h1g + (size_t)((s-4)&1)*VECW + bg*3072, bufH, tid);
      // bufX holds h0(s-2), staged post-flag at step s-1
    }
    __syncthreads();

    // ---- fused matmul: waves 0-3 gh, waves 4-7 gi (concurrent) ----
    if (wv<4){ if (gG) mm9(bufH, wRow, gatesG,        wv4, kq, bb); }
    else     { if (gI) mm9(bufX, wRow, gatesI[s&1],   wv4, kq, bb); }
    __syncthreads();

    // ---- nonlinearity + publish (48 threads: 8 b x 6 col-pairs) ----
    if (gG && tid<48){
      const int b = tid&7, j = tid>>3;
      float hv2[2];
#pragma unroll
      for (int e=0;e<2;e++){
        const int cc = 2*j+e;
        const float gir = gatesI[(s-1)&1][cc    ][b] + biasS[cc];
        const float giz = gatesI[(s-1)&1][12+cc][b] + biasS[12+cc];
        const float gin = gatesI[(s-1)&1][24+cc][b] + biasS[24+cc];
        const float ghr = gatesG[cc    ][b] + biasS[36+cc];
        const float ghz = gatesG[12+cc][b] + biasS[48+cc];
        const float ghn = gatesG[24+cc][b] + biasS[60+cc];
        const float r = sigm(gir+ghr);
        const float z = sigm(giz+ghz);
        const float n = tanhf(fmaf(r, ghn, gin));
        const float hp = hprev[b][cc];
        hv2[e] = fmaf(z, hp - n, n);
        hprev[b][cc] = hv2[e];
      }
      const unsigned pk = pack2(hv2[0], hv2[1]);
      if (L==0){
        unsigned* hOutW = h0g + (size_t)(s&3)*VECW;
        __hip_atomic_store(hOutW + (b0+b)*384 + cg*6 + j, pk,
                           __ATOMIC_RELAXED, __HIP_MEMORY_SCOPE_AGENT);
      } else {
        unsigned* hOutW = h1g + (size_t)((s-3)&1)*VECW;
        __hip_atomic_store(hOutW + (b0+b)*384 + cg*6 + j, pk,
                           __ATOMIC_RELAXED, __HIP_MEMORY_SCOPE_AGENT);
        if (s==Tz+2){                          // h1(Tz-1) -> fp32 for LN
          h1f[(b0+b)*Ez + c0 + 2*j    ] = hv2[0];
          h1f[(b0+b)*Ez + c0 + 2*j + 1] = hv2[1];
        }
      }
    }

    // ---- arrive: drain publish stores, then flag ----
    __syncthreads();
    if (tid==0)
      __hip_atomic_store(flags + bx, (unsigned)(s+1),
                         __ATOMIC_RELAXED, __HIP_MEMORY_SCOPE_AGENT);

    // ---- post-flag (hidden under next barrier/relay) ----
    if (L==0){
      if (s<=Tz-3){
#pragma unroll
        for (int k=0;k<3;k++){
          const int i4 = tid + (k<<9);
          const int b = i4/192, c4 = i4 - b*192;
          const int row = idx[(b0+b)*Tz + (s+2)];
          *(float4*)&bufX[b][c4<<2] = *(const float4*)(wte + (size_t)row*Ez + (c4<<2));
        }
      }
    } else {
      // stage h0(s-1) for next step's gI; visibility by go(s) (already
      // detected at step-s start: h0(s-1) published before flag(s)).
      if (s>=1 && s<=Tz)
        stage8(h0g + (size_t)((s-1)&3)*VECW + bg*3072, bufX, tid);
    }
  }
}

// LayerNorm of final h1 (fp32) -> ln
__global__ __launch_bounds__(256) void finalize_ln(
    const float* __restrict__ h1, const float* __restrict__ g,
    float* __restrict__ ln)
{
  const int tid=threadIdx.x, wv=tid>>6, lane=tid&63;
  for (int b=wv; b<Bz; b+=4){
    float sum=0.f;
    for (int c=lane;c<Ez;c+=64) sum += h1[b*Ez+c];
#pragma unroll
    for (int off=32; off; off>>=1) sum += __shfl_xor(sum, off);
    const float mu = sum/(float)Ez;
    float s2=0.f;
    for (int c=lane;c<Ez;c+=64){ const float d=h1[b*Ez+c]-mu; s2=fmaf(d,d,s2); }
#pragma unroll
    for (int off=32; off; off>>=1) s2 += __shfl_xor(s2, off);
    const float inv = rsqrtf(s2/(float)Ez + LN_EPS);
    for (int c=lane;c<Ez;c+=64) ln[b*Ez+c] = (h1[b*Ez+c]-mu)*inv*g[c];
  }
}

// logits[b,v] = dot(ln[b,:], wte[v,:]) ; 64 rows per block, 16 rows per wave.
__global__ __launch_bounds__(256) void lm_head(
    const float* __restrict__ ln, const float* __restrict__ wte,
    float* __restrict__ out)
{
  __shared__ float sLn[Bz][EP];
  const int tid=threadIdx.x;
  for (int i4=tid; i4<Bz*Ez/4; i4+=256){
    const int b = i4/(Ez/4), c = (i4 - b*(Ez/4))<<2;
    *(float4*)(&sLn[b][c]) = *(const float4*)(ln + b*Ez + c);
  }
  __syncthreads();
  const int wv=tid>>6, lane=tid&63, rr=lane>>4, cl=lane&15;
  const int vbase = blockIdx.x*64 + wv*16 + rr;
  float acc[4][16];
#pragma unroll
  for (int k=0;k<4;k++)
#pragma unroll
    for (int b=0;b<16;b++) acc[k][b]=0.f;

  for (int j=0;j<12;j++){
    const int c = (cl<<2) + (j<<6);
    float4 w4[4];
#pragma unroll
    for (int k=0;k<4;k++){
      const int v = vbase + 4*k;
      if (v < Vz) w4[k] = *(const float4*)(wte + (size_t)v*Ez + c);
      else { w4[k].x=w4[k].y=w4[k].z=w4[k].w=0.f; }
    }
#pragma unroll
    for (int b=0;b<16;b++){
      const float4 hv = *(const float4*)(&sLn[b][c]);
#pragma unroll
      for (int k=0;k<4;k++) acc[k][b] = dot4acc(acc[k][b], w4[k], hv);
    }
  }
#pragma unroll
  for (int off=1; off<16; off<<=1)
#pragma unroll
    for (int k=0;k<4;k++)
#pragma unroll
      for (int b=0;b<16;b++) acc[k][b] += __shfl_xor(acc[k][b], off);

  if (cl==0){
#pragma unroll
    for (int k=0;k<4;k++){
      const int v = vbase + 4*k;
      if (v < Vz){
#pragma unroll
        for (int b=0;b<16;b++) out[(size_t)b*Vz + v] = acc[k][b];
      }
    }
  }
}

extern "C" void kernel_launch(void* const* d_in, const int* in_sizes, int n_in,
                              void* d_out, int out_size, void* d_ws, size_t ws_size,
                              hipStream_t stream) {
  const int*   idx = (const int*)  d_in[0];
  const float* wte = (const float*)d_in[1];
  const float* Wih = (const float*)d_in[2];
  const float* bih = (const float*)d_in[3];
  const float* Whh = (const float*)d_in[4];
  const float* bhh = (const float*)d_in[5];
  const float* g   = (const float*)d_in[6];
  float* out = (float*)d_out;

  unsigned* flags = (unsigned*)d_ws;            // words [0,256)
  unsigned* go    = (unsigned*)d_ws + 512;      // words [512,2560): 64 lines
  unsigned* h0g   = (unsigned*)d_ws + 4096;     // 4 x 6144 words (quad buf)
  unsigned* h1g   = h0g + 4*VECW;               // 2 x 6144 words
  float*    h1f   = (float*)(h1g + 2*VECW);     // B*E fp32 final h1
  float*    ln    = h1f + VEC;                  // B*E fp32

  (void)hipMemsetAsync(d_ws, 0, 16384, stream); // reset flags + go lines

  void* args[] = {(void*)&idx,(void*)&wte,(void*)&Wih,(void*)&bih,
                  (void*)&Whh,(void*)&bhh,(void*)&h0g,(void*)&h1g,
                  (void*)&h1f,(void*)&flags,(void*)&go};
  (void)hipLaunchCooperativeKernel((void*)gru_scan, dim3(NBK), dim3(512), args, 0, stream);

  finalize_ln<<<1, 256, 0, stream>>>(h1f, g, ln);
  lm_head<<<786, 256, 0, stream>>>(ln, wte, out);
}

// Round 27
// 10535.726 us; speedup vs baseline: 1.2604x; 1.0158x over previous
//
#include <hip/hip_runtime.h>
#include <hip/hip_fp16.h>
#include <math.h>

#define Bz 16
#define Tz 1024
#define Ez 768
#define E3 2304
#define Vz 50257
#define NBK 256          // 256 blocks (coop grid must be <=256: R26 lesson)
#define LN_EPS 1e-5f
#define VEC (Bz*Ez)      // 12288 floats per full h vector
#define VECW 6144        // packed fp16: u32 words per full h vector
#define EP 772           // padded LDS row stride (fp32)
#define BS 8             // batches per block
#define CW 12            // columns per block

__device__ __forceinline__ float dot4acc(float acc, float4 w, float4 h){
  acc = fmaf(w.x,h.x,acc); acc = fmaf(w.y,h.y,acc);
  acc = fmaf(w.z,h.z,acc); acc = fmaf(w.w,h.w,acc);
  return acc;
}
__device__ __forceinline__ float sigm(float x){ return 1.0f/(1.0f+expf(-x)); }

__device__ __forceinline__ unsigned pack2(float a, float b){
  __half2 h = __floats2half2_rn(a, b);
  union{__half2 h2; unsigned u;} cv; cv.h2 = h; return cv.u;
}
__device__ __forceinline__ float2 unpack2(unsigned u){
  union{unsigned u; __half2 h2;} cv; cv.u = u;
  return __half22float2(cv.h2);
}

// ---- Staging envelope (empirical): scalar 32-bit relaxed-atomic loads with
// IMMEDIATE LDS stores. Proven widths: 2/3/4; failures were batch-then-store
// >=8, inline-asm, DMA. This round: 6-wide immediate-store body (1 RTT). ----

// Critical-path stage: one body, 6 outstanding loads -> 6 stores (1 RTT).
__device__ __forceinline__ void stage8w6(const unsigned* __restrict__ src,
                                         float (*dst)[EP], int tid){
  const int u0 = tid;
  const int u1 = tid + 512;
  const int u2 = tid + 1024;
  const int u3 = tid + 1536;
  const int u4 = tid + 2048;
  const int u5 = tid + 2560;
  const unsigned a0 = __hip_atomic_load(src+u0, __ATOMIC_RELAXED, __HIP_MEMORY_SCOPE_AGENT);
  const unsigned a1 = __hip_atomic_load(src+u1, __ATOMIC_RELAXED, __HIP_MEMORY_SCOPE_AGENT);
  const unsigned a2 = __hip_atomic_load(src+u2, __ATOMIC_RELAXED, __HIP_MEMORY_SCOPE_AGENT);
  const unsigned a3 = __hip_atomic_load(src+u3, __ATOMIC_RELAXED, __HIP_MEMORY_SCOPE_AGENT);
  const unsigned a4 = __hip_atomic_load(src+u4, __ATOMIC_RELAXED, __HIP_MEMORY_SCOPE_AGENT);
  const unsigned a5 = __hip_atomic_load(src+u5, __ATOMIC_RELAXED, __HIP_MEMORY_SCOPE_AGENT);
  {const int b=u0/384, c=(u0-b*384)<<1; const float2 f=unpack2(a0); dst[b][c]=f.x; dst[b][c+1]=f.y;}
  {const int b=u1/384, c=(u1-b*384)<<1; const float2 f=unpack2(a1); dst[b][c]=f.x; dst[b][c+1]=f.y;}
  {const int b=u2/384, c=(u2-b*384)<<1; const float2 f=unpack2(a2); dst[b][c]=f.x; dst[b][c+1]=f.y;}
  {const int b=u3/384, c=(u3-b*384)<<1; const float2 f=unpack2(a3); dst[b][c]=f.x; dst[b][c+1]=f.y;}
  {const int b=u4/384, c=(u4-b*384)<<1; const float2 f=unpack2(a4); dst[b][c]=f.x; dst[b][c+1]=f.y;}
  {const int b=u5/384, c=(u5-b*384)<<1; const float2 f=unpack2(a5); dst[b][c]=f.x; dst[b][c+1]=f.y;}
}

// Off-critical-path stage (post-flag): proven 2 bodies of 3.
__device__ __forceinline__ void stage8(const unsigned* __restrict__ src,
                                       float (*dst)[EP], int tid){
#pragma unroll
  for (int k=0;k<2;k++){
    const int u0 = tid + k*1536;
    const int u1 = u0 + 512;
    const int u2 = u0 + 1024;
    const unsigned a0 = __hip_atomic_load(src+u0, __ATOMIC_RELAXED, __HIP_MEMORY_SCOPE_AGENT);
    const unsigned a1 = __hip_atomic_load(src+u1, __ATOMIC_RELAXED, __HIP_MEMORY_SCOPE_AGENT);
    const unsigned a2 = __hip_atomic_load(src+u2, __ATOMIC_RELAXED, __HIP_MEMORY_SCOPE_AGENT);
    {const int b=u0/384, c=(u0-b*384)<<1; const float2 f=unpack2(a0); dst[b][c]=f.x; dst[b][c+1]=f.y;}
    {const int b=u1/384, c=(u1-b*384)<<1; const float2 f=unpack2(a1); dst[b][c]=f.x; dst[b][c+1]=f.y;}
    {const int b=u2/384, c=(u2-b*384)<<1; const float2 f=unpack2(a2); dst[b][c]=f.x; dst[b][c+1]=f.y;}
  }
}

__device__ __forceinline__ void zero8(float (*dst)[EP], int tid){
#pragma unroll
  for (int k=0;k<6;k++){
    const int u = tid + (k<<9);
    const int b = u/384, c = (u-b*384)<<1;
    dst[b][c] = 0.f; dst[b][c+1] = 0.f;
  }
}

// 9 rows per wave (wave-group row base wv4*9), 8 batches (bb -> 2 each).
__device__ __forceinline__ void mm9(const float (*V)[EP],
                                    const float* const (&wRow)[9],
                                    float (*gOut)[9],
                                    int wv4, int kq, int bb){
  float acc[9][2];
#pragma unroll
  for (int r=0;r<9;r++){ acc[r][0]=0.f; acc[r][1]=0.f; }
#pragma unroll 4
  for (int j=0;j<12;j++){
    const int kk = (j<<6) + (kq<<2);
    float4 w4[9];
#pragma unroll
    for (int r=0;r<9;r++) w4[r] = *(const float4*)(wRow[r] + kk);
#pragma unroll
    for (int bi=0;bi<2;bi++){
      const float4 hv = *(const float4*)&V[bb*2+bi][kk];
#pragma unroll
      for (int r=0;r<9;r++) acc[r][bi] = dot4acc(acc[r][bi], w4[r], hv);
    }
  }
#pragma unroll
  for (int r=0;r<9;r++)
#pragma unroll
    for (int bi=0;bi<2;bi++){
      float a = acc[r][bi];
      a += __shfl_xor(a,1); a += __shfl_xor(a,2);
      a += __shfl_xor(a,4); a += __shfl_xor(a,8);
      acc[r][bi]=a;
    }
  if (kq==0){
#pragma unroll
    for (int r=0;r<9;r++)
#pragma unroll
      for (int bi=0;bi<2;bi++) gOut[wv4*9+r][bb*2+bi] = acc[r][bi];
  }
}

// ---------------------------------------------------------------------------
// Persistent cooperative scan = R25 verbatim (fused phase, lag-3 L1,
// post-flag h0 stage, two-level relay on block 0), with:
//  * critical own-h stage: single 6-wide immediate-store body (1 RTT, was 2)
//  * worker go-poll sleep quantum 2 -> 1
// ---------------------------------------------------------------------------
__global__ __launch_bounds__(512) void gru_scan(
    const int* __restrict__ idx, const float* __restrict__ wte,
    const float* __restrict__ Wih, const float* __restrict__ bih,
    const float* __restrict__ Whh, const float* __restrict__ bhh,
    unsigned* __restrict__ h0g, unsigned* __restrict__ h1g,
    float* __restrict__ h1f,
    unsigned* __restrict__ flags, unsigned* __restrict__ go)
{
  __shared__ float bufX[BS][EP];      // gi input: x(s+1) (L0) / h0(s-2) (L1)
  __shared__ float bufH[BS][EP];      // gh input: own-layer h_prev
  __shared__ float gatesG[36][9];     // gh (this step)
  __shared__ float gatesI[2][36][9];  // gi ping-pong (s&1 = write slot)
  __shared__ float biasS[72];
  __shared__ float hprev[BS][CW];     // own (batch,col) h, exact fp32

  const int tid = threadIdx.x, bx = blockIdx.x;
  const int L = bx>>7, sub = bx&127;
  const int bg = sub>>6, cg = sub&63;
  const int c0 = cg*CW, b0 = bg*BS;
  const int wv = tid>>6, lane = tid&63, kq = lane&15, bb = lane>>4;
  const int wv4 = wv & 3;

  const float* WihL = Wih + (size_t)L*E3*Ez;
  const float* WhhL = Whh + (size_t)L*E3*Ez;

  // waves 0-3 -> Whh rows (gatesG); waves 4-7 -> Wih rows (gatesI).
  const float* wRow[9];
  {
    const float* Wb = (wv < 4) ? WhhL : WihL;
#pragma unroll
    for (int r=0;r<9;r++){
      const int m = wv4*9 + r, g = m/12, cc = m - g*12;
      wRow[r] = Wb + (size_t)(g*Ez + c0 + cc)*Ez;
    }
  }
  if (tid<72){
    const int mat = tid/36, mm = tid%36, g = mm/12, cc = mm-g*12;
    biasS[tid] = (mat ? bhh : bih)[L*E3 + g*Ez + c0 + cc];
  }
  if (tid<96) hprev[tid&7][tid>>3] = 0.f;

  // ---- prologue (L0): gatesI[1] <- Wih . x(0); then load x(1) ----
  if (L==0){
#pragma unroll
    for (int k=0;k<3;k++){
      const int i4 = tid + (k<<9);
      const int b = i4/192, c4 = i4 - b*192;
      const int row = idx[(b0+b)*Tz];
      *(float4*)&bufX[b][c4<<2] = *(const float4*)(wte + (size_t)row*Ez + (c4<<2));
    }
    __syncthreads();
    if (wv>=4) mm9(bufX, wRow, gatesI[1], wv4, kq, bb);
    __syncthreads();
#pragma unroll
    for (int k=0;k<3;k++){
      const int i4 = tid + (k<<9);
      const int b = i4/192, c4 = i4 - b*192;
      const int row = idx[(b0+b)*Tz + 1];
      *(float4*)&bufX[b][c4<<2] = *(const float4*)(wte + (size_t)row*Ez + (c4<<2));
    }
  }
  __syncthreads();

  for (int s=0; s<=Tz+2; ++s){
    // ---- grid wait (two-level relay + replicated go lines) ----
    if (s>0){
      const unsigned tgt = (unsigned)s;
      if (bx==0){
        if (tid<64){
          const unsigned* f = flags + (tid<<2);
          for(;;){
            const unsigned a0 = __hip_atomic_load(f+0, __ATOMIC_RELAXED, __HIP_MEMORY_SCOPE_AGENT);
            const unsigned a1 = __hip_atomic_load(f+1, __ATOMIC_RELAXED, __HIP_MEMORY_SCOPE_AGENT);
            const unsigned a2 = __hip_atomic_load(f+2, __ATOMIC_RELAXED, __HIP_MEMORY_SCOPE_AGENT);
            const unsigned a3 = __hip_atomic_load(f+3, __ATOMIC_RELAXED, __HIP_MEMORY_SCOPE_AGENT);
            const int ok = (a0>=tgt) & (a1>=tgt) & (a2>=tgt) & (a3>=tgt);
            if (__all(ok)) break;
            __builtin_amdgcn_s_sleep(1);
          }
          __hip_atomic_store(go + (tid<<5), tgt,
                             __ATOMIC_RELAXED, __HIP_MEMORY_SCOPE_AGENT);
        }
      } else {
        if (tid==0){
          const unsigned* gp = go + ((bx&63)<<5);
          while (__hip_atomic_load(gp, __ATOMIC_RELAXED, __HIP_MEMORY_SCOPE_AGENT) < tgt)
            __builtin_amdgcn_s_sleep(1);
        }
      }
      __syncthreads();
    }

    // ---- activity windows ----
    const bool gG = (L==0) ? (s<=Tz-1) : (s>=3);               // gh + nonlin
    const bool gI = (L==0) ? (s<=Tz-2) : (s>=2 && s<=Tz+1);    // gi for next step

    // ---- critical stage: OWN-layer h only (single 6-wide body) ----
    if (L==0){
      if (s==0)            zero8(bufH, tid);
      else if (s<=Tz-1)    stage8w6(h0g + (size_t)((s-1)&3)*VECW + bg*3072, bufH, tid);
      // bufX holds x(s+1), prefetched (cached)
    } else {
      if (s==3)                 zero8(bufH, tid);
      else if (s>=4 && s<=Tz+2) stage8w6(h1g + (size_t)((s-4)&1)*VECW + bg*3072, bufH, tid);
      // bufX holds h0(s-2), staged post-flag at step s-1
    }
    __syncthreads();

    // ---- fused matmul: waves 0-3 gh, waves 4-7 gi (concurrent) ----
    if (wv<4){ if (gG) mm9(bufH, wRow, gatesG,        wv4, kq, bb); }
    else     { if (gI) mm9(bufX, wRow, gatesI[s&1],   wv4, kq, bb); }
    __syncthreads();

    // ---- nonlinearity + publish (48 threads: 8 b x 6 col-pairs) ----
    if (gG && tid<48){
      const int b = tid&7, j = tid>>3;
      float hv2[2];
#pragma unroll
      for (int e=0;e<2;e++){
        const int cc = 2*j+e;
        const float gir = gatesI[(s-1)&1][cc    ][b] + biasS[cc];
        const float giz = gatesI[(s-1)&1][12+cc][b] + biasS[12+cc];
        const float gin = gatesI[(s-1)&1][24+cc][b] + biasS[24+cc];
        const float ghr = gatesG[cc    ][b] + biasS[36+cc];
        const float ghz = gatesG[12+cc][b] + biasS[48+cc];
        const float ghn = gatesG[24+cc][b] + biasS[60+cc];
        const float r = sigm(gir+ghr);
        const float z = sigm(giz+ghz);
        const float n = tanhf(fmaf(r, ghn, gin));
        const float hp = hprev[b][cc];
        hv2[e] = fmaf(z, hp - n, n);
        hprev[b][cc] = hv2[e];
      }
      const unsigned pk = pack2(hv2[0], hv2[1]);
      if (L==0){
        unsigned* hOutW = h0g + (size_t)(s&3)*VECW;
        __hip_atomic_store(hOutW + (b0+b)*384 + cg*6 + j, pk,
                           __ATOMIC_RELAXED, __HIP_MEMORY_SCOPE_AGENT);
      } else {
        unsigned* hOutW = h1g + (size_t)((s-3)&1)*VECW;
        __hip_atomic_store(hOutW + (b0+b)*384 + cg*6 + j, pk,
                           __ATOMIC_RELAXED, __HIP_MEMORY_SCOPE_AGENT);
        if (s==Tz+2){                          // h1(Tz-1) -> fp32 for LN
          h1f[(b0+b)*Ez + c0 + 2*j    ] = hv2[0];
          h1f[(b0+b)*Ez + c0 + 2*j + 1] = hv2[1];
        }
      }
    }

    // ---- arrive: drain publish stores, then flag ----
    __syncthreads();
    if (tid==0)
      __hip_atomic_store(flags + bx, (unsigned)(s+1),
                         __ATOMIC_RELAXED, __HIP_MEMORY_SCOPE_AGENT);

    // ---- post-flag (hidden under next barrier/relay) ----
    if (L==0){
      if (s<=Tz-3){
#pragma unroll
        for (int k=0;k<3;k++){
          const int i4 = tid + (k<<9);
          const int b = i4/192, c4 = i4 - b*192;
          const int row = idx[(b0+b)*Tz + (s+2)];
          *(float4*)&bufX[b][c4<<2] = *(const float4*)(wte + (size_t)row*Ez + (c4<<2));
        }
      }
    } else {
      // stage h0(s-1) for next step's gI; visibility by go(s) (already
      // detected at step-s start: h0(s-1) published before flag(s)).
      if (s>=1 && s<=Tz)
        stage8(h0g + (size_t)((s-1)&3)*VECW + bg*3072, bufX, tid);
    }
  }
}

// LayerNorm of final h1 (fp32) -> ln
__global__ __launch_bounds__(256) void finalize_ln(
    const float* __restrict__ h1, const float* __restrict__ g,
    float* __restrict__ ln)
{
  const int tid=threadIdx.x, wv=tid>>6, lane=tid&63;
  for (int b=wv; b<Bz; b+=4){
    float sum=0.f;
    for (int c=lane;c<Ez;c+=64) sum += h1[b*Ez+c];
#pragma unroll
    for (int off=32; off; off>>=1) sum += __shfl_xor(sum, off);
    const float mu = sum/(float)Ez;
    float s2=0.f;
    for (int c=lane;c<Ez;c+=64){ const float d=h1[b*Ez+c]-mu; s2=fmaf(d,d,s2); }
#pragma unroll
    for (int off=32; off; off>>=1) s2 += __shfl_xor(s2, off);
    const float inv = rsqrtf(s2/(float)Ez + LN_EPS);
    for (int c=lane;c<Ez;c+=64) ln[b*Ez+c] = (h1[b*Ez+c]-mu)*inv*g[c];
  }
}

// logits[b,v] = dot(ln[b,:], wte[v,:]) ; 64 rows per block, 16 rows per wave.
__global__ __launch_bounds__(256) void lm_head(
    const float* __restrict__ ln, const float* __restrict__ wte,
    float* __restrict__ out)
{
  __shared__ float sLn[Bz][EP];
  const int tid=threadIdx.x;
  for (int i4=tid; i4<Bz*Ez/4; i4+=256){
    const int b = i4/(Ez/4), c = (i4 - b*(Ez/4))<<2;
    *(float4*)(&sLn[b][c]) = *(const float4*)(ln + b*Ez + c);
  }
  __syncthreads();
  const int wv=tid>>6, lane=tid&63, rr=lane>>4, cl=lane&15;
  const int vbase = blockIdx.x*64 + wv*16 + rr;
  float acc[4][16];
#pragma unroll
  for (int k=0;k<4;k++)
#pragma unroll
    for (int b=0;b<16;b++) acc[k][b]=0.f;

  for (int j=0;j<12;j++){
    const int c = (cl<<2) + (j<<6);
    float4 w4[4];
#pragma unroll
    for (int k=0;k<4;k++){
      const int v = vbase + 4*k;
      if (v < Vz) w4[k] = *(const float4*)(wte + (size_t)v*Ez + c);
      else { w4[k].x=w4[k].y=w4[k].z=w4[k].w=0.f; }
    }
#pragma unroll
    for (int b=0;b<16;b++){
      const float4 hv = *(const float4*)(&sLn[b][c]);
#pragma unroll
      for (int k=0;k<4;k++) acc[k][b] = dot4acc(acc[k][b], w4[k], hv);
    }
  }
#pragma unroll
  for (int off=1; off<16; off<<=1)
#pragma unroll
    for (int k=0;k<4;k++)
#pragma unroll
      for (int b=0;b<16;b++) acc[k][b] += __shfl_xor(acc[k][b], off);

  if (cl==0){
#pragma unroll
    for (int k=0;k<4;k++){
      const int v = vbase + 4*k;
      if (v < Vz){
#pragma unroll
        for (int b=0;b<16;b++) out[(size_t)b*Vz + v] = acc[k][b];
      }
    }
  }
}

extern "C" void kernel_launch(void* const* d_in, const int* in_sizes, int n_in,
                              void* d_out, int out_size, void* d_ws, size_t ws_size,
                              hipStream_t stream) {
  const int*   idx = (const int*)  d_in[0];
  const float* wte = (const float*)d_in[1];
  const float* Wih = (const float*)d_in[2];
  const float* bih = (const float*)d_in[3];
  const float* Whh = (const float*)d_in[4];
  const float* bhh = (const float*)d_in[5];
  const float* g   = (const float*)d_in[6];
  float* out = (float*)d_out;

  unsigned* flags = (unsigned*)d_ws;            // words [0,256)
  unsigned* go    = (unsigned*)d_ws + 512;      // words [512,2560): 64 lines
  unsigned* h0g   = (unsigned*)d_ws + 4096;     // 4 x 6144 words (quad buf)
  unsigned* h1g   = h0g + 4*VECW;               // 2 x 6144 words
  float*    h1f   = (float*)(h1g + 2*VECW);     // B*E fp32 final h1
  float*    ln    = h1f + VEC;                  // B*E fp32

  (void)hipMemsetAsync(d_ws, 0, 16384, stream); // reset flags + go lines

  void* args[] = {(void*)&idx,(void*)&wte,(void*)&Wih,(void*)&bih,
                  (void*)&Whh,(void*)&bhh,(void*)&h0g,(void*)&h1g,
                  (void*)&h1f,(void*)&flags,(void*)&go};
  (void)hipLaunchCooperativeKernel((void*)gru_scan, dim3(NBK), dim3(512), args, 0, stream);

  finalize_ln<<<1, 256, 0, stream>>>(h1f, g, ln);
  lm_head<<<786, 256, 0, stream>>>(ln, wte, out);
}